// Round 16
// baseline (605.335 us; speedup 1.0000x reference)
//
#include <hip/hip_runtime.h>

#define NNODES 50000
#define NEDGES 800000
#define NGRAPHS 1000
#define BN_EPS 1e-5f
#define MPAD 50048   // 391 * 128

typedef unsigned short us_t;
typedef us_t us8 __attribute__((ext_vector_type(8)));
typedef us_t us4 __attribute__((ext_vector_type(4)));
typedef __bf16 bf16x8 __attribute__((ext_vector_type(8)));
typedef float f32x4 __attribute__((ext_vector_type(4)));

__device__ __forceinline__ float b2f(us_t u) {
    union { unsigned int i; float f; } v;
    v.i = ((unsigned int)u) << 16;
    return v.f;
}
__device__ __forceinline__ us_t f2b(float x) {
    unsigned int u = __float_as_uint(x);
    unsigned int r = u + 0x7FFFu + ((u >> 16) & 1u);
    return (us_t)(r >> 16);
}
__device__ __forceinline__ float h2f(us_t u) {
    _Float16 h;
    __builtin_memcpy(&h, &u, 2);
    return (float)h;
}
__device__ __forceinline__ us_t f2h(float x) {
    _Float16 h = (_Float16)x;
    us_t u;
    __builtin_memcpy(&u, &h, 2);
    return u;
}
__device__ __forceinline__ bf16x8 as_bf(us8 v) {
    union { us8 u; bf16x8 b; } c;
    c.u = v;
    return c.b;
}

// async global->LDS, 16B per lane; LDS dst = wave-uniform base + lane*16
__device__ __forceinline__ void glds16(const us_t* g, us_t* l) {
    __builtin_amdgcn_global_load_lds(
        (const __attribute__((address_space(1))) void*)g,
        (__attribute__((address_space(3))) void*)l, 16, 0, 0);
}

// ================= elementwise =================

__global__ void zero_f32(float* __restrict__ p, int n) {
    int i = blockIdx.x * blockDim.x + threadIdx.x;
    if (i < n) p[i] = 0.f;
}

// ================= CSR build =================

__global__ void csr_hist(const int* __restrict__ dst, int* __restrict__ deg, int E) {
    int e = blockIdx.x * blockDim.x + threadIdx.x;
    if (e < E) atomicAdd(&deg[dst[e]], 1);
}

__global__ void csr_scan1(const int* __restrict__ deg, int* __restrict__ tmpscan,
                          int* __restrict__ chunkTot, int n) {
    __shared__ int sm[1024];
    int i = blockIdx.x * 1024 + threadIdx.x;
    int v = (i < n) ? deg[i] : 0;
    sm[threadIdx.x] = v;
    __syncthreads();
    for (int off = 1; off < 1024; off <<= 1) {
        int add = (threadIdx.x >= off) ? sm[threadIdx.x - off] : 0;
        __syncthreads();
        sm[threadIdx.x] += add;
        __syncthreads();
    }
    if (i < n) tmpscan[i] = sm[threadIdx.x];
    if (threadIdx.x == 1023) chunkTot[blockIdx.x] = sm[1023];
}

__global__ void csr_scan2(int* __restrict__ chunkTot, int nchunks) {
    if (threadIdx.x == 0 && blockIdx.x == 0) {
        int run = 0;
        for (int c = 0; c < nchunks; c++) {
            int t = chunkTot[c];
            chunkTot[c] = run;
            run += t;
        }
    }
}

__global__ void csr_scan3(const int* __restrict__ deg, const int* __restrict__ tmpscan,
                          const int* __restrict__ chunkTot, int* __restrict__ rowptr,
                          int* __restrict__ cursor, int n) {
    int i = blockIdx.x * blockDim.x + threadIdx.x;
    if (i < n) {
        int inc = tmpscan[i] + chunkTot[i >> 10];
        rowptr[i + 1] = inc;
        cursor[i] = inc - deg[i];
        if (i == 0) rowptr[0] = 0;
    }
}

__global__ void csr_fill(const int* __restrict__ src, const int* __restrict__ dst,
                         int* __restrict__ cursor, int* __restrict__ eidx, int E) {
    int e = blockIdx.x * blockDim.x + threadIdx.x;
    if (e < E) {
        int pos = atomicAdd(&cursor[dst[e]], 1);
        eidx[pos] = src[e];
    }
}

// ================= all weight converts in one kernel: W[K][N] -> Wt[N][K] bf16 ==========

__global__ void wt_convert_all(const float* __restrict__ w2, const float* __restrict__ w3,
                               const float* __restrict__ w4, const float* __restrict__ w5,
                               const float* __restrict__ w6,
                               us_t* __restrict__ o2, us_t* __restrict__ o3,
                               us_t* __restrict__ o4, us_t* __restrict__ o5,
                               us_t* __restrict__ o6) {
    int i = blockIdx.x * blockDim.x + threadIdx.x;
    if (i < 16384) {                       // 128x128
        int k = i >> 7, n = i & 127;
        o2[n * 128 + k] = f2b(w2[i]);
    } else if (i < 49152) {                // 128x256
        int j = i - 16384; int k = j >> 8, n = j & 255;
        o3[n * 128 + k] = f2b(w3[j]);
    } else if (i < 114688) {               // 256x256
        int j = i - 49152; int k = j >> 8, n = j & 255;
        o4[n * 256 + k] = f2b(w4[j]);
    } else if (i < 180224) {
        int j = i - 114688; int k = j >> 8, n = j & 255;
        o5[n * 256 + k] = f2b(w5[j]);
    } else if (i < 245760) {
        int j = i - 180224; int k = j >> 8, n = j & 255;
        o6[n * 256 + k] = f2b(w6[j]);
    }
}

// ================= GIN gather with fused BN+relu (F=128, us8 / 16B lanes) ==========

__global__ void gin_gather_bn128(const us_t* __restrict__ z, const float* __restrict__ sums,
                                 const float* __restrict__ sumsq, const float* __restrict__ gw,
                                 const float* __restrict__ bw, float invM,
                                 const int* __restrict__ rowptr, const int* __restrict__ eidx,
                                 us_t* __restrict__ out) {
    int ln = threadIdx.x >> 4;       // 16 nodes/block
    int fp = threadIdx.x & 15;
    int n = blockIdx.x * 16 + ln;
    if (n >= NNODES) return;
    int f0 = fp * 8;
    float s[8], t[8];
    #pragma unroll
    for (int q = 0; q < 8; q++) {
        float m = sums[f0 + q] * invM;
        float va = sumsq[f0 + q] * invM - m * m;
        s[q] = gw[f0 + q] * rsqrtf(va + BN_EPS);
        t[q] = bw[f0 + q] - m * s[q];
    }
    const us_t* zf = z + f0;
    float a[8];
    us8 v = *(const us8*)&zf[(size_t)n * 128];
    #pragma unroll
    for (int q = 0; q < 8; q++) a[q] = fmaxf(0.f, b2f(v[q]) * s[q] + t[q]);
    int p0 = rowptr[n], p1 = rowptr[n + 1];
    int p = p0;
    for (; p + 4 <= p1; p += 4) {
        int e0 = eidx[p], e1 = eidx[p + 1], e2 = eidx[p + 2], e3 = eidx[p + 3];
        us8 u0 = *(const us8*)&zf[(size_t)e0 * 128];
        us8 u1 = *(const us8*)&zf[(size_t)e1 * 128];
        us8 u2 = *(const us8*)&zf[(size_t)e2 * 128];
        us8 u3 = *(const us8*)&zf[(size_t)e3 * 128];
        #pragma unroll
        for (int q = 0; q < 8; q++)
            a[q] += fmaxf(0.f, b2f(u0[q]) * s[q] + t[q]) +
                    fmaxf(0.f, b2f(u1[q]) * s[q] + t[q]) +
                    fmaxf(0.f, b2f(u2[q]) * s[q] + t[q]) +
                    fmaxf(0.f, b2f(u3[q]) * s[q] + t[q]);
    }
    for (; p < p1; p++) {
        us8 u = *(const us8*)&zf[(size_t)eidx[p] * 128];
        #pragma unroll
        for (int q = 0; q < 8; q++) a[q] += fmaxf(0.f, b2f(u[q]) * s[q] + t[q]);
    }
    us8 o;
    #pragma unroll
    for (int q = 0; q < 8; q++) o[q] = f2b(a[q]);
    *(us8*)&out[(size_t)n * 128 + f0] = o;
}

// ================= GIN gather with fused BN+relu (F=256, us8 / 16B lanes) ==========

__global__ void gin_gather_bn256(const us_t* __restrict__ z, const float* __restrict__ sums,
                                 const float* __restrict__ sumsq, const float* __restrict__ gw,
                                 const float* __restrict__ bw, float invM,
                                 const int* __restrict__ rowptr, const int* __restrict__ eidx,
                                 us_t* __restrict__ out) {
    int ln = threadIdx.x >> 5;       // 0..7
    int fp = threadIdx.x & 31;
    int n = blockIdx.x * 8 + ln;
    if (n >= NNODES) return;
    int f0 = fp * 8;
    float s[8], t[8];
    #pragma unroll
    for (int q = 0; q < 8; q++) {
        float m = sums[f0 + q] * invM;
        float va = sumsq[f0 + q] * invM - m * m;
        s[q] = gw[f0 + q] * rsqrtf(va + BN_EPS);
        t[q] = bw[f0 + q] - m * s[q];
    }
    const us_t* zf = z + f0;
    float a[8];
    us8 v = *(const us8*)&zf[(size_t)n * 256];
    #pragma unroll
    for (int q = 0; q < 8; q++) a[q] = fmaxf(0.f, b2f(v[q]) * s[q] + t[q]);
    int p0 = rowptr[n], p1 = rowptr[n + 1];
    int p = p0;
    for (; p + 4 <= p1; p += 4) {
        int e0 = eidx[p], e1 = eidx[p + 1], e2 = eidx[p + 2], e3 = eidx[p + 3];
        us8 u0 = *(const us8*)&zf[(size_t)e0 * 256];
        us8 u1 = *(const us8*)&zf[(size_t)e1 * 256];
        us8 u2 = *(const us8*)&zf[(size_t)e2 * 256];
        us8 u3 = *(const us8*)&zf[(size_t)e3 * 256];
        #pragma unroll
        for (int q = 0; q < 8; q++)
            a[q] += fmaxf(0.f, b2f(u0[q]) * s[q] + t[q]) +
                    fmaxf(0.f, b2f(u1[q]) * s[q] + t[q]) +
                    fmaxf(0.f, b2f(u2[q]) * s[q] + t[q]) +
                    fmaxf(0.f, b2f(u3[q]) * s[q] + t[q]);
    }
    for (; p < p1; p++) {
        us8 u = *(const us8*)&zf[(size_t)eidx[p] * 256];
        #pragma unroll
        for (int q = 0; q < 8; q++) a[q] += fmaxf(0.f, b2f(u[q]) * s[q] + t[q]);
    }
    us8 o;
    #pragma unroll
    for (int q = 0; q < 8; q++) o[q] = f2b(a[q]);
    *(us8*)&out[(size_t)n * 256 + f0] = o;
}

// F=11 fp32 gather (input features)
__global__ void gin_gather11(const float* __restrict__ x, const int* __restrict__ rowptr,
                             const int* __restrict__ eidx, float* __restrict__ out) {
    int local = threadIdx.x >> 4;
    int lane = threadIdx.x & 15;
    int n = blockIdx.x * 16 + local;
    if (n >= NNODES) return;
    int p0 = rowptr[n], p1 = rowptr[n + 1];
    float acc = (lane < 11) ? x[n * 11 + lane] : 0.f;
    for (int p = p0; p < p1; p++) {
        int src = eidx[p];
        if (lane < 11) acc += x[src * 11 + lane];
    }
    if (lane < 11) out[n * 11 + lane] = acc;
}

// ================= layer-1 GEMM: [M,11] fp32 @ [11,128] + b -> fp16 + exact stats ======

__global__ __launch_bounds__(256) void gemm11(const float* __restrict__ A,
                                              const float* __restrict__ W,
                                              const float* __restrict__ b,
                                              us_t* __restrict__ C,
                                              float* __restrict__ sums,
                                              float* __restrict__ sumsq) {
    __shared__ float sW[11 * 128];
    __shared__ float sArows[64 * 11];
    int tid = threadIdx.x;
    for (int i = tid; i < 11 * 128; i += 256) sW[i] = W[i];
    int r0 = blockIdx.x * 64;
    for (int i = tid; i < 64 * 11; i += 256) {
        int r = i / 11, c = i - r * 11;
        sArows[i] = (r0 + r < NNODES) ? A[(r0 + r) * 11 + c] : 0.f;
    }
    __syncthreads();
    int col = tid & 127;
    int half = tid >> 7;
    float bias = b[col];
    float cs = 0.f, cq = 0.f;
    for (int rr = half * 32; rr < half * 32 + 32; rr++) {
        int row = r0 + rr;
        if (row < NNODES) {
            float acc = bias;
            #pragma unroll
            for (int k = 0; k < 11; k++) acc += sArows[rr * 11 + k] * sW[k * 128 + col];
            C[(size_t)row * 128 + col] = f2h(acc);
            cs += acc;
            cq += acc * acc;
        }
    }
    __syncthreads();
    sArows[tid] = cs;
    sArows[256 + tid] = cq;
    __syncthreads();
    if (tid < 128) {
        atomicAdd(&sums[tid], sArows[tid] + sArows[tid + 128]);
        atomicAdd(&sumsq[tid], sArows[256 + tid] + sArows[256 + tid + 128]);
    }
}

// ================= MFMA GEMM v10 — double-buffered LDS, 1 barrier/k-step ==========
// C[M,N] = A'[M,K_] @ Wt[N,K_]^T + bias, + exact column stats (fp32 acc).
// 128x128 tile, BK=32, 4 waves of 64x64 (4x4 MFMA 16x16x32).
// Two 8KB LDS tile buffers; each iteration issues NEXT tile's staging loads
// (glds for B / A-bf16; raw reg loads for A-fp16) BEFORE the MFMAs, writes the
// transformed A after the MFMAs, then ONE barrier. Load latency overlaps MFMA.
// AMODE 0: A bf16 (glds). AMODE 2: A fp16 + BN+relu -> bf16 (reg staging).
// OMODE 0: C bf16. OMODE 2: C fp16. C staged in LDS (stride 136) -> us8 streams.
// COLS=2: block remap so paired column-blocks share an XCD (A L2 reuse).

template <int K_, int AMODE, int OMODE, int COLS>
__global__ __launch_bounds__(256, 4) void gemm_v10(
    const void* __restrict__ Ap, const us_t* __restrict__ Wt,
    const float* __restrict__ bias,
    const float* __restrict__ sums_in, const float* __restrict__ sumsq_in,
    const float* __restrict__ gma, const float* __restrict__ bet, float invM,
    us_t* __restrict__ Cp, float* __restrict__ sums, float* __restrict__ sumsq,
    int M, int N, int nrows) {
    __shared__ us_t smem[16384];                  // 32 KB: tile0 | tile1 (8192 us each)
    __shared__ float sST[(AMODE == 2) ? 2 * K_ : 2];

    int rowblk, colblk;
    if (COLS == 1) {
        rowblk = blockIdx.x;
        colblk = 0;
    } else {
        int g = blockIdx.x;
        rowblk = (g >> 4) * 8 + (g & 7);
        colblk = (g >> 3) & 1;
        if (rowblk >= nrows) return;   // uniform whole-block exit (before barriers)
    }
    const int bm = rowblk * 128;
    const int bn = colblk * 128;

    const int tid = threadIdx.x;
    const int lane = tid & 63;
    const int wave = tid >> 6;
    const int wm = wave >> 1, wn = wave & 1;
    const int lrow = lane & 15, lquad = lane >> 4;

    if (AMODE == 2) {
        if (tid < K_) {
            float m = sums_in[tid] * invM;
            float va = sumsq_in[tid] * invM - m * m;
            float sc = gma[tid] * rsqrtf(va + BN_EPS);
            sST[tid] = sc;
            sST[K_ + tid] = bet[tid] - m * sc;
        }
        __syncthreads();
    }

    f32x4 acc[4][4] = {};

    const int r0c = tid >> 2, q0c = tid & 3;
    const int r1c = (tid + 256) >> 2, q1c = tid & 3;
    constexpr int NK = K_ / 32;

    auto stage_glds = [&](int kt, us_t* tb) {
        us_t* sBb = tb + 4096;
        const int k0 = kt * 32;
        glds16(&Wt[(size_t)(bn + r0c) * K_ + k0 + q0c * 8], &sBb[(wave * 64) * 8]);
        glds16(&Wt[(size_t)(bn + r1c) * K_ + k0 + q1c * 8], &sBb[(256 + wave * 64) * 8]);
        if (AMODE == 0) {
            const us_t* A = (const us_t*)Ap;
            glds16(&A[(size_t)(bm + r0c) * K_ + k0 + q0c * 8], &tb[(wave * 64) * 8]);
            glds16(&A[(size_t)(bm + r1c) * K_ + k0 + q1c * 8], &tb[(256 + wave * 64) * 8]);
        }
    };
    auto load_raw = [&](int kt, us8* raw) {
        const us_t* A = (const us_t*)Ap;
        const int k0 = kt * 32;
        raw[0] = *(const us8*)&A[(size_t)(bm + r0c) * K_ + k0 + q0c * 8];
        raw[1] = *(const us8*)&A[(size_t)(bm + r1c) * K_ + k0 + q1c * 8];
    };
    auto xform_write = [&](int kt, const us8* raw, us_t* tb) {
        const int k0 = kt * 32;
        #pragma unroll
        for (int i = 0; i < 2; i++) {
            int kk = k0 + ((i == 0) ? q0c : q1c) * 8;
            float4 s0 = *(const float4*)&sST[kk];
            float4 s1 = *(const float4*)&sST[kk + 4];
            float4 t0 = *(const float4*)&sST[K_ + kk];
            float4 t1 = *(const float4*)&sST[K_ + kk + 4];
            us8 o;
            o[0] = f2b(fmaxf(0.f, h2f(raw[i][0]) * s0.x + t0.x));
            o[1] = f2b(fmaxf(0.f, h2f(raw[i][1]) * s0.y + t0.y));
            o[2] = f2b(fmaxf(0.f, h2f(raw[i][2]) * s0.z + t0.z));
            o[3] = f2b(fmaxf(0.f, h2f(raw[i][3]) * s0.w + t0.w));
            o[4] = f2b(fmaxf(0.f, h2f(raw[i][4]) * s1.x + t1.x));
            o[5] = f2b(fmaxf(0.f, h2f(raw[i][5]) * s1.y + t1.y));
            o[6] = f2b(fmaxf(0.f, h2f(raw[i][6]) * s1.z + t1.z));
            o[7] = f2b(fmaxf(0.f, h2f(raw[i][7]) * s1.w + t1.w));
            *(us8*)&tb[(size_t)((i == 0) ? tid : (tid + 256)) * 8] = o;
        }
    };

    // ---- prologue: stage tile 0 ----
    stage_glds(0, smem);
    us8 raw[2];
    if (AMODE == 2) {
        load_raw(0, raw);
        xform_write(0, raw, smem);
    }
    __syncthreads();

    #pragma unroll
    for (int kt = 0; kt < NK; kt++) {
        us_t* cur = smem + ((kt & 1) ? 8192 : 0);
        us_t* nxt = smem + ((kt & 1) ? 0 : 8192);
        if (kt + 1 < NK) {
            stage_glds(kt + 1, nxt);
            if (AMODE == 2) load_raw(kt + 1, raw);
        }
        // ---- fragments + MFMA on current tile ----
        us_t* sA = cur;
        us_t* sB = cur + 4096;
        bf16x8 af[4], bfr[4];
        #pragma unroll
        for (int i = 0; i < 4; i++)
            af[i] = as_bf(*(const us8*)&sA[(wm * 64 + i * 16 + lrow) * 32 + lquad * 8]);
        #pragma unroll
        for (int j = 0; j < 4; j++)
            bfr[j] = as_bf(*(const us8*)&sB[(wn * 64 + j * 16 + lrow) * 32 + lquad * 8]);
        #pragma unroll
        for (int i = 0; i < 4; i++)
            #pragma unroll
            for (int j = 0; j < 4; j++)
                acc[i][j] = __builtin_amdgcn_mfma_f32_16x16x32_bf16(af[i], bfr[j],
                                                                    acc[i][j], 0, 0, 0);
        if (AMODE == 2 && kt + 1 < NK) xform_write(kt + 1, raw, nxt);
        __syncthreads();
    }

    // ---- stats (exact, from fp32 acc + bias) ----
    #pragma unroll
    for (int j = 0; j < 4; j++) {
        int col = bn + wn * 64 + j * 16 + lrow;
        float bcol = bias[col];
        float cs = 0.f, cq = 0.f;
        #pragma unroll
        for (int i = 0; i < 4; i++) {
            int rb = bm + wm * 64 + i * 16 + lquad * 4;
            #pragma unroll
            for (int r = 0; r < 4; r++) {
                if (rb + r < M) {
                    float zv = acc[i][j][r] + bcol;
                    cs += zv;
                    cq += zv * zv;
                }
            }
        }
        cs += __shfl_xor(cs, 16); cs += __shfl_xor(cs, 32);
        cq += __shfl_xor(cq, 16); cq += __shfl_xor(cq, 32);
        if (lquad == 0) {
            atomicAdd(&sums[col], cs);
            atomicAdd(&sumsq[col], cq);
        }
    }

    // ---- C store via LDS staging: 2 passes of 64 rows x 128 cols (stride 136) ----
    #pragma unroll
    for (int p = 0; p < 2; p++) {
        __syncthreads();   // prior pass stream-out / K-loop reads complete
        if (wm == p) {
            #pragma unroll
            for (int j = 0; j < 4; j++) {
                int coll = wn * 64 + j * 16 + lrow;
                float bcol = bias[bn + coll];
                #pragma unroll
                for (int i = 0; i < 4; i++) {
                    int rl = i * 16 + lquad * 4;
                    #pragma unroll
                    for (int r = 0; r < 4; r++) {
                        float zv = acc[i][j][r] + bcol;
                        smem[(rl + r) * 136 + coll] = (OMODE == 0) ? f2b(zv) : f2h(zv);
                    }
                }
            }
        }
        __syncthreads();
        #pragma unroll
        for (int k = 0; k < 4; k++) {      // 1024 us8 chunks, 4/thread
            int c = tid + 256 * k;
            int row = c >> 4, cw = c & 15;
            int grow = bm + p * 64 + row;
            if (grow < M)
                *(us8*)&Cp[(size_t)grow * N + bn + cw * 8] =
                    *(const us8*)&smem[row * 136 + cw * 8];
        }
    }
}

// ================= pool (fp16 z in, BN finalize+apply+relu fused, atomic out) ==========

__global__ void pool_bn_h(const us_t* __restrict__ z, const float* __restrict__ sums,
                          const float* __restrict__ sumsq, const float* __restrict__ gw,
                          const float* __restrict__ bw, float invM,
                          const int* __restrict__ batch, float* __restrict__ hg) {
    int f = threadIdx.x;  // 256
    float m = sums[f] * invM;
    float va = sumsq[f] * invM - m * m;
    float sv = gw[f] * rsqrtf(va + BN_EPS);
    float tv = bw[f] - m * sv;
    int n0 = blockIdx.x * 32;
    int n1 = min(n0 + 32, NNODES);
    float acc = 0.f;
    int gc = batch[n0];
    for (int n = n0; n < n1; n++) {
        int g = batch[n];
        if (g != gc) {
            atomicAdd(&hg[gc * 256 + f], acc);
            acc = 0.f;
            gc = g;
        }
        acc += fmaxf(0.f, h2f(z[(size_t)n * 256 + f]) * sv + tv);
    }
    atomicAdd(&hg[gc * 256 + f], acc);
}

// ================= head GEMM fp32 (M=1000,K=256,N=128) + stats =================

#define GBM 128
#define GBN 128
#define GBK 16
#define LDA 132

__global__ __launch_bounds__(256) void gemm_f32_head(
    const float* __restrict__ A, const float* __restrict__ W, const float* __restrict__ bias,
    float* __restrict__ C, float* __restrict__ sums, float* __restrict__ sumsq,
    int M, int K, int N) {
    __shared__ float smem[2 * GBK * LDA];
    float* As = smem;
    float* Ws = smem + GBK * LDA;

    const int bm = blockIdx.y * GBM;
    const int bn = blockIdx.x * GBN;
    const int tid = threadIdx.x;
    const int tm = tid >> 4;
    const int tn = tid & 15;

    float acc[2][2][4][4] = {};

    for (int k0 = 0; k0 < K; k0 += GBK) {
        #pragma unroll
        for (int i = 0; i < 2; i++) {
            int id = tid + 256 * i;
            int row = id >> 2;
            int kq = id & 3;
            int gr = bm + row;
            int kk = k0 + kq * 4;
            float4 a4 = make_float4(0.f, 0.f, 0.f, 0.f);
            if (gr < M && kk < K) a4 = *(const float4*)&A[(size_t)gr * K + kk];
            As[(kq * 4 + 0) * LDA + row] = a4.x;
            As[(kq * 4 + 1) * LDA + row] = a4.y;
            As[(kq * 4 + 2) * LDA + row] = a4.z;
            As[(kq * 4 + 3) * LDA + row] = a4.w;
        }
        #pragma unroll
        for (int i = 0; i < 2; i++) {
            int id = tid + 256 * i;
            int kl = id >> 5;
            int c = id & 31;
            int kk = k0 + kl;
            float4 w4 = make_float4(0.f, 0.f, 0.f, 0.f);
            if (kk < K && bn + c * 4 < N) w4 = *(const float4*)&W[(size_t)kk * N + bn + c * 4];
            *(float4*)&Ws[kl * LDA + c * 4] = w4;
        }
        __syncthreads();
        #pragma unroll
        for (int k = 0; k < GBK; k++) {
            float4 a0 = *(float4*)&As[k * LDA + tm * 4];
            float4 a1 = *(float4*)&As[k * LDA + 64 + tm * 4];
            float4 w0 = *(float4*)&Ws[k * LDA + tn * 4];
            float4 w1 = *(float4*)&Ws[k * LDA + 64 + tn * 4];
            float ar[2][4] = {{a0.x, a0.y, a0.z, a0.w}, {a1.x, a1.y, a1.z, a1.w}};
            float wr[2][4] = {{w0.x, w0.y, w0.z, w0.w}, {w1.x, w1.y, w1.z, w1.w}};
            #pragma unroll
            for (int ri = 0; ri < 2; ri++)
                #pragma unroll
                for (int ci = 0; ci < 2; ci++)
                    #pragma unroll
                    for (int ii = 0; ii < 4; ii++)
                        #pragma unroll
                        for (int jj = 0; jj < 4; jj++)
                            acc[ri][ci][ii][jj] += ar[ri][ii] * wr[ci][jj];
        }
        __syncthreads();
    }

    float colsum[2][4] = {};
    float colsq[2][4] = {};
    #pragma unroll
    for (int ci = 0; ci < 2; ci++) {
        int colbase = bn + ci * 64 + tn * 4;
        if (colbase >= N) continue;
        float4 b4 = *(const float4*)&bias[colbase];
        float br[4] = {b4.x, b4.y, b4.z, b4.w};
        #pragma unroll
        for (int ri = 0; ri < 2; ri++) {
            #pragma unroll
            for (int ii = 0; ii < 4; ii++) {
                int row = bm + ri * 64 + tm * 4 + ii;
                if (row < M) {
                    float z0 = acc[ri][ci][ii][0] + br[0];
                    float z1 = acc[ri][ci][ii][1] + br[1];
                    float z2 = acc[ri][ci][ii][2] + br[2];
                    float z3 = acc[ri][ci][ii][3] + br[3];
                    *(float4*)&C[(size_t)row * N + colbase] = make_float4(z0, z1, z2, z3);
                    colsum[ci][0] += z0; colsq[ci][0] += z0 * z0;
                    colsum[ci][1] += z1; colsq[ci][1] += z1 * z1;
                    colsum[ci][2] += z2; colsq[ci][2] += z2 * z2;
                    colsum[ci][3] += z3; colsq[ci][3] += z3 * z3;
                }
            }
        }
    }
    __syncthreads();
    float* ps = smem;
    float* pq = smem + 2048;
    #pragma unroll
    for (int ci = 0; ci < 2; ci++)
        #pragma unroll
        for (int jj = 0; jj < 4; jj++) {
            int cl = ci * 64 + tn * 4 + jj;
            ps[tm * 128 + cl] = colsum[ci][jj];
            pq[tm * 128 + cl] = colsq[ci][jj];
        }
    __syncthreads();
    if (tid < 128 && bn + tid < N) {
        float s = 0.f, q = 0.f;
        #pragma unroll
        for (int i = 0; i < 16; i++) {
            s += ps[i * 128 + tid];
            q += pq[i * 128 + tid];
        }
        atomicAdd(&sums[bn + tid], s);
        atomicAdd(&sumsq[bn + tid], q);
    }
}

// ================= final head GEMV (BN finalize+apply+relu fused) =================

__global__ void final_gemv_raw(const float* __restrict__ hg2, const float* __restrict__ sums,
                               const float* __restrict__ sumsq, const float* __restrict__ gw,
                               const float* __restrict__ bw, float invM,
                               const float* __restrict__ fw2, const float* __restrict__ fb2,
                               float* __restrict__ out) {
    int g = blockIdx.x;
    int l = threadIdx.x;  // 64
    float m0 = sums[l] * invM, va0 = sumsq[l] * invM - m0 * m0;
    float s0 = gw[l] * rsqrtf(va0 + BN_EPS), t0 = bw[l] - m0 * s0;
    float m1 = sums[64 + l] * invM, va1 = sumsq[64 + l] * invM - m1 * m1;
    float s1 = gw[64 + l] * rsqrtf(va1 + BN_EPS), t1 = bw[64 + l] - m1 * s1;
    float a0 = fmaxf(0.f, hg2[g * 128 + l] * s0 + t0) * fw2[l];
    float a1 = fmaxf(0.f, hg2[g * 128 + 64 + l] * s1 + t1) * fw2[64 + l];
    float v = a0 + a1;
    #pragma unroll
    for (int o = 32; o > 0; o >>= 1) v += __shfl_down(v, o);
    if (l == 0) out[g] = v + fb2[0];
}

// ================= launch =================

extern "C" void kernel_launch(void* const* d_in, const int* in_sizes, int n_in,
                              void* d_out, int out_size, void* d_ws, size_t ws_size,
                              hipStream_t stream) {
    const float* x = (const float*)d_in[0];
    const int* ei = (const int*)d_in[1];
    const int* batch = (const int*)d_in[2];
    const int* esrc = ei;
    const int* edst = ei + NEDGES;

    const float* l1w = (const float*)d_in[3],  *l1b = (const float*)d_in[4],
               * l1g = (const float*)d_in[5],  *l1be = (const float*)d_in[6];
    const float* l2w = (const float*)d_in[7],  *l2b = (const float*)d_in[8],
               * l2g = (const float*)d_in[9],  *l2be = (const float*)d_in[10];
    const float* l3w = (const float*)d_in[11], *l3b = (const float*)d_in[12],
               * l3g = (const float*)d_in[13], *l3be = (const float*)d_in[14];
    const float* l4w = (const float*)d_in[15], *l4b = (const float*)d_in[16],
               * l4g = (const float*)d_in[17], *l4be = (const float*)d_in[18];
    const float* l5w = (const float*)d_in[19], *l5b = (const float*)d_in[20],
               * l5g = (const float*)d_in[21], *l5be = (const float*)d_in[22];
    const float* l6w = (const float*)d_in[23], *l6b = (const float*)d_in[24],
               * l6g = (const float*)d_in[25], *l6be = (const float*)d_in[26];
    const float* fw1 = (const float*)d_in[27], *fb1 = (const float*)d_in[28],
               * fg  = (const float*)d_in[29], *fbe = (const float*)d_in[30];
    const float* fw2 = (const float*)d_in[31], *fb2 = (const float*)d_in[32];

    // ---- workspace carve ----
    // F0h: fp16 z1/z3/z5 [MPAD,256]
    // U region [MPAD,512] us: Ba (bf16 agg) | Bz (bf16 z2/z4, then fp16 z6)
    us_t* F0h = (us_t*)d_ws;                          // [MPAD,256] fp16
    us_t* Ba = F0h + (size_t)MPAD * 256;              // [MPAD,256] bf16 (agg)
    us_t* Bz = Ba + (size_t)MPAD * 256;               // [MPAD,256] bf16 z2/z4 -> fp16 z6
    us_t* wt2 = Bz + (size_t)MPAD * 256;              // [128][128]
    us_t* wt3 = wt2 + 128 * 128;                      // [256][128]
    us_t* wt4 = wt3 + 256 * 128;                      // [256][256]
    us_t* wt5 = wt4 + 256 * 256;
    us_t* wt6 = wt5 + 256 * 256;
    float* agg11 = (float*)(wt6 + 256 * 256);         // [50000][11]
    float* hg = agg11 + (size_t)NNODES * 11;          // [1000][256]
    float* hg2 = hg + NGRAPHS * 256;                  // [1000][128]
    float* stats = hg2 + NGRAPHS * 128;               // 7 x 512 (sums|sumsq)
    int* deg = (int*)(stats + 7 * 512);               // [50001]
    int* rowptr = deg + (NNODES + 1);
    int* cursor = rowptr + (NNODES + 1);
    int* chunkTot = cursor + (NNODES + 1);            // [64]
    int* tmpscan = chunkTot + 64;
    int* eidx = tmpscan + (NNODES + 1);               // [800000]

    // zero hg + hg2 + stats + deg (contiguous)
    {
        int zn = NGRAPHS * 256 + NGRAPHS * 128 + 7 * 512 + (NNODES + 1);
        zero_f32<<<(zn + 255) / 256, 256, 0, stream>>>(hg, zn);
    }

    // CSR
    csr_hist<<<(NEDGES + 255) / 256, 256, 0, stream>>>(edst, deg, NEDGES);
    int nchunks = (NNODES + 1023) / 1024;
    csr_scan1<<<nchunks, 1024, 0, stream>>>(deg, tmpscan, chunkTot, NNODES);
    csr_scan2<<<1, 64, 0, stream>>>(chunkTot, nchunks);
    csr_scan3<<<(NNODES + 255) / 256, 256, 0, stream>>>(deg, tmpscan, chunkTot, rowptr,
                                                        cursor, NNODES);
    csr_fill<<<(NEDGES + 255) / 256, 256, 0, stream>>>(esrc, edst, cursor, eidx, NEDGES);

    // weight converts
    wt_convert_all<<<(245760 + 255) / 256, 256, 0, stream>>>(l2w, l3w, l4w, l5w, l6w,
                                                             wt2, wt3, wt4, wt5, wt6);

    auto st = [&](int i) { return stats + i * 512; };
    const float invN = 1.0f / (float)NNODES;
    const float invG = 1.0f / (float)NGRAPHS;
    const int NRB = MPAD / 128;              // 391
    const int NSWZ = ((NRB + 7) / 8) * 16;   // 784 swizzled blocks for COLS=2

    // ---- conv1: agg(x) -> z1=F0h fp16 [M,128] -> [BN0 fused] l2 -> z2=Bz bf16 ----
    gin_gather11<<<(NNODES + 15) / 16, 256, 0, stream>>>(x, rowptr, eidx, agg11);
    gemm11<<<(NNODES + 63) / 64, 256, 0, stream>>>(agg11, l1w, l1b, F0h, st(0), st(0) + 256);
    gemm_v10<128, 2, 0, 1><<<NRB, 256, 0, stream>>>(
        F0h, wt2, l2b, st(0), st(0) + 256, l1g, l1be, invN,
        Bz, st(1), st(1) + 256, NNODES, 128, NRB);

    // ---- conv2: gather(BN1) z2 -> agg2=Ba bf16 [M,128] -> l3 -> z3=F0h fp16 [M,256]
    //            -> [BN2 fused] l4 -> z4=Bz bf16 [M,256] ----
    gin_gather_bn128<<<(NNODES + 15) / 16, 256, 0, stream>>>(
        Bz, st(1), st(1) + 256, l2g, l2be, invN, rowptr, eidx, Ba);
    gemm_v10<128, 0, 2, 2><<<NSWZ, 256, 0, stream>>>(
        Ba, wt3, l3b, nullptr, nullptr, nullptr, nullptr, 0.f,
        F0h, st(2), st(2) + 256, NNODES, 256, NRB);
    gemm_v10<256, 2, 0, 2><<<NSWZ, 256, 0, stream>>>(
        F0h, wt4, l4b, st(2), st(2) + 256, l3g, l3be, invN,
        Bz, st(3), st(3) + 256, NNODES, 256, NRB);

    // ---- conv3: gather(BN3) z4 -> agg3=Ba bf16 [M,256] -> l5 -> z5=F0h fp16
    //            -> [BN4 fused] l6 -> z6=Bz fp16 (z4 dead) ----
    gin_gather_bn256<<<(NNODES + 7) / 8, 256, 0, stream>>>(
        Bz, st(3), st(3) + 256, l4g, l4be, invN, rowptr, eidx, Ba);
    gemm_v10<256, 0, 2, 2><<<NSWZ, 256, 0, stream>>>(
        Ba, wt5, l5b, nullptr, nullptr, nullptr, nullptr, 0.f,
        F0h, st(4), st(4) + 256, NNODES, 256, NRB);
    gemm_v10<256, 2, 2, 2><<<NSWZ, 256, 0, stream>>>(
        F0h, wt6, l6b, st(4), st(4) + 256, l5g, l5be, invN,
        Bz, st(5), st(5) + 256, NNODES, 256, NRB);

    // ---- pool (BN5 fused, fp16 z6) + head ----
    pool_bn_h<<<(NNODES + 31) / 32, 256, 0, stream>>>(
        Bz, st(5), st(5) + 256, l6g, l6be, invN, batch, hg);
    gemm_f32_head<<<dim3(1, 8), 256, 0, stream>>>(hg, fw1, fb1, hg2, st(6), st(6) + 256,
                                                  NGRAPHS, 256, 128);
    final_gemv_raw<<<NGRAPHS, 64, 0, stream>>>(hg2, st(6), st(6) + 256, fg, fbe, invG,
                                               fw2, fb2, (float*)d_out);
}

// Round 17
// 540.531 us; speedup vs baseline: 1.1199x; 1.1199x over previous
//
#include <hip/hip_runtime.h>

#define NNODES 50000
#define NEDGES 800000
#define NGRAPHS 1000
#define BN_EPS 1e-5f
#define MPAD 50048   // 391 * 128

typedef unsigned short us_t;
typedef us_t us8 __attribute__((ext_vector_type(8)));
typedef us_t us4 __attribute__((ext_vector_type(4)));
typedef __bf16 bf16x8 __attribute__((ext_vector_type(8)));
typedef float f32x4 __attribute__((ext_vector_type(4)));

__device__ __forceinline__ float b2f(us_t u) {
    union { unsigned int i; float f; } v;
    v.i = ((unsigned int)u) << 16;
    return v.f;
}
__device__ __forceinline__ us_t f2b(float x) {
    unsigned int u = __float_as_uint(x);
    unsigned int r = u + 0x7FFFu + ((u >> 16) & 1u);
    return (us_t)(r >> 16);
}
__device__ __forceinline__ float h2f(us_t u) {
    _Float16 h;
    __builtin_memcpy(&h, &u, 2);
    return (float)h;
}
__device__ __forceinline__ us_t f2h(float x) {
    _Float16 h = (_Float16)x;
    us_t u;
    __builtin_memcpy(&u, &h, 2);
    return u;
}
__device__ __forceinline__ bf16x8 as_bf(us8 v) {
    union { us8 u; bf16x8 b; } c;
    c.u = v;
    return c.b;
}

// async global->LDS, 16B per lane; LDS dst = wave-uniform base + lane*16
__device__ __forceinline__ void glds16(const us_t* g, us_t* l) {
    __builtin_amdgcn_global_load_lds(
        (const __attribute__((address_space(1))) void*)g,
        (__attribute__((address_space(3))) void*)l, 16, 0, 0);
}

// ================= elementwise =================

__global__ void zero_f32(float* __restrict__ p, int n) {
    int i = blockIdx.x * blockDim.x + threadIdx.x;
    if (i < n) p[i] = 0.f;
}

// ================= CSR build =================

__global__ void csr_hist(const int* __restrict__ dst, int* __restrict__ deg, int E) {
    int e = blockIdx.x * blockDim.x + threadIdx.x;
    if (e < E) atomicAdd(&deg[dst[e]], 1);
}

__global__ void csr_scan1(const int* __restrict__ deg, int* __restrict__ tmpscan,
                          int* __restrict__ chunkTot, int n) {
    __shared__ int sm[1024];
    int i = blockIdx.x * 1024 + threadIdx.x;
    int v = (i < n) ? deg[i] : 0;
    sm[threadIdx.x] = v;
    __syncthreads();
    for (int off = 1; off < 1024; off <<= 1) {
        int add = (threadIdx.x >= off) ? sm[threadIdx.x - off] : 0;
        __syncthreads();
        sm[threadIdx.x] += add;
        __syncthreads();
    }
    if (i < n) tmpscan[i] = sm[threadIdx.x];
    if (threadIdx.x == 1023) chunkTot[blockIdx.x] = sm[1023];
}

// scan3 with chunk-prefix folded in (replaces the old serial csr_scan2)
__global__ void csr_scan3(const int* __restrict__ deg, const int* __restrict__ tmpscan,
                          const int* __restrict__ chunkTot, int* __restrict__ rowptr,
                          int* __restrict__ cursor, int n, int nchunks) {
    __shared__ int sct[64];
    if (threadIdx.x < nchunks) sct[threadIdx.x] = chunkTot[threadIdx.x];
    __syncthreads();
    int i = blockIdx.x * blockDim.x + threadIdx.x;
    if (i < n) {
        int chunk = i >> 10;
        int pre = 0;
        for (int c = 0; c < chunk; c++) pre += sct[c];
        int inc = tmpscan[i] + pre;
        rowptr[i + 1] = inc;
        cursor[i] = inc - deg[i];
        if (i == 0) rowptr[0] = 0;
    }
}

__global__ void csr_fill(const int* __restrict__ src, const int* __restrict__ dst,
                         int* __restrict__ cursor, int* __restrict__ eidx, int E) {
    int e = blockIdx.x * blockDim.x + threadIdx.x;
    if (e < E) {
        int pos = atomicAdd(&cursor[dst[e]], 1);
        eidx[pos] = src[e];
    }
}

// ================= all weight converts in one kernel: W[K][N] -> Wt[N][K] bf16 ==========

__global__ void wt_convert_all(const float* __restrict__ w2, const float* __restrict__ w3,
                               const float* __restrict__ w4, const float* __restrict__ w5,
                               const float* __restrict__ w6,
                               us_t* __restrict__ o2, us_t* __restrict__ o3,
                               us_t* __restrict__ o4, us_t* __restrict__ o5,
                               us_t* __restrict__ o6) {
    int i = blockIdx.x * blockDim.x + threadIdx.x;
    if (i < 16384) {                       // 128x128
        int k = i >> 7, n = i & 127;
        o2[n * 128 + k] = f2b(w2[i]);
    } else if (i < 49152) {                // 128x256
        int j = i - 16384; int k = j >> 8, n = j & 255;
        o3[n * 128 + k] = f2b(w3[j]);
    } else if (i < 114688) {               // 256x256
        int j = i - 49152; int k = j >> 8, n = j & 255;
        o4[n * 256 + k] = f2b(w4[j]);
    } else if (i < 180224) {
        int j = i - 114688; int k = j >> 8, n = j & 255;
        o5[n * 256 + k] = f2b(w5[j]);
    } else if (i < 245760) {
        int j = i - 180224; int k = j >> 8, n = j & 255;
        o6[n * 256 + k] = f2b(w6[j]);
    }
}

// ================= GIN gather with fused BN+relu (F=128, us8 / 16B lanes) ==========

__global__ void gin_gather_bn128(const us_t* __restrict__ z, const float* __restrict__ sums,
                                 const float* __restrict__ sumsq, const float* __restrict__ gw,
                                 const float* __restrict__ bw, float invM,
                                 const int* __restrict__ rowptr, const int* __restrict__ eidx,
                                 us_t* __restrict__ out) {
    int ln = threadIdx.x >> 4;       // 16 nodes/block
    int fp = threadIdx.x & 15;
    int n = blockIdx.x * 16 + ln;
    if (n >= NNODES) return;
    int f0 = fp * 8;
    float s[8], t[8];
    #pragma unroll
    for (int q = 0; q < 8; q++) {
        float m = sums[f0 + q] * invM;
        float va = sumsq[f0 + q] * invM - m * m;
        s[q] = gw[f0 + q] * rsqrtf(va + BN_EPS);
        t[q] = bw[f0 + q] - m * s[q];
    }
    const us_t* zf = z + f0;
    float a[8];
    us8 v = *(const us8*)&zf[(size_t)n * 128];
    #pragma unroll
    for (int q = 0; q < 8; q++) a[q] = fmaxf(0.f, b2f(v[q]) * s[q] + t[q]);
    int p0 = rowptr[n], p1 = rowptr[n + 1];
    int p = p0;
    for (; p + 4 <= p1; p += 4) {
        int e0 = eidx[p], e1 = eidx[p + 1], e2 = eidx[p + 2], e3 = eidx[p + 3];
        us8 u0 = *(const us8*)&zf[(size_t)e0 * 128];
        us8 u1 = *(const us8*)&zf[(size_t)e1 * 128];
        us8 u2 = *(const us8*)&zf[(size_t)e2 * 128];
        us8 u3 = *(const us8*)&zf[(size_t)e3 * 128];
        #pragma unroll
        for (int q = 0; q < 8; q++)
            a[q] += fmaxf(0.f, b2f(u0[q]) * s[q] + t[q]) +
                    fmaxf(0.f, b2f(u1[q]) * s[q] + t[q]) +
                    fmaxf(0.f, b2f(u2[q]) * s[q] + t[q]) +
                    fmaxf(0.f, b2f(u3[q]) * s[q] + t[q]);
    }
    for (; p < p1; p++) {
        us8 u = *(const us8*)&zf[(size_t)eidx[p] * 128];
        #pragma unroll
        for (int q = 0; q < 8; q++) a[q] += fmaxf(0.f, b2f(u[q]) * s[q] + t[q]);
    }
    us8 o;
    #pragma unroll
    for (int q = 0; q < 8; q++) o[q] = f2b(a[q]);
    *(us8*)&out[(size_t)n * 128 + f0] = o;
}

// ================= GIN gather with fused BN+relu (F=256, us8 / 16B lanes) ==========

__global__ void gin_gather_bn256(const us_t* __restrict__ z, const float* __restrict__ sums,
                                 const float* __restrict__ sumsq, const float* __restrict__ gw,
                                 const float* __restrict__ bw, float invM,
                                 const int* __restrict__ rowptr, const int* __restrict__ eidx,
                                 us_t* __restrict__ out) {
    int ln = threadIdx.x >> 5;       // 0..7
    int fp = threadIdx.x & 31;
    int n = blockIdx.x * 8 + ln;
    if (n >= NNODES) return;
    int f0 = fp * 8;
    float s[8], t[8];
    #pragma unroll
    for (int q = 0; q < 8; q++) {
        float m = sums[f0 + q] * invM;
        float va = sumsq[f0 + q] * invM - m * m;
        s[q] = gw[f0 + q] * rsqrtf(va + BN_EPS);
        t[q] = bw[f0 + q] - m * s[q];
    }
    const us_t* zf = z + f0;
    float a[8];
    us8 v = *(const us8*)&zf[(size_t)n * 256];
    #pragma unroll
    for (int q = 0; q < 8; q++) a[q] = fmaxf(0.f, b2f(v[q]) * s[q] + t[q]);
    int p0 = rowptr[n], p1 = rowptr[n + 1];
    int p = p0;
    for (; p + 4 <= p1; p += 4) {
        int e0 = eidx[p], e1 = eidx[p + 1], e2 = eidx[p + 2], e3 = eidx[p + 3];
        us8 u0 = *(const us8*)&zf[(size_t)e0 * 256];
        us8 u1 = *(const us8*)&zf[(size_t)e1 * 256];
        us8 u2 = *(const us8*)&zf[(size_t)e2 * 256];
        us8 u3 = *(const us8*)&zf[(size_t)e3 * 256];
        #pragma unroll
        for (int q = 0; q < 8; q++)
            a[q] += fmaxf(0.f, b2f(u0[q]) * s[q] + t[q]) +
                    fmaxf(0.f, b2f(u1[q]) * s[q] + t[q]) +
                    fmaxf(0.f, b2f(u2[q]) * s[q] + t[q]) +
                    fmaxf(0.f, b2f(u3[q]) * s[q] + t[q]);
    }
    for (; p < p1; p++) {
        us8 u = *(const us8*)&zf[(size_t)eidx[p] * 256];
        #pragma unroll
        for (int q = 0; q < 8; q++) a[q] += fmaxf(0.f, b2f(u[q]) * s[q] + t[q]);
    }
    us8 o;
    #pragma unroll
    for (int q = 0; q < 8; q++) o[q] = f2b(a[q]);
    *(us8*)&out[(size_t)n * 256 + f0] = o;
}

// F=11 fp32 gather (input features)
__global__ void gin_gather11(const float* __restrict__ x, const int* __restrict__ rowptr,
                             const int* __restrict__ eidx, float* __restrict__ out) {
    int local = threadIdx.x >> 4;
    int lane = threadIdx.x & 15;
    int n = blockIdx.x * 16 + local;
    if (n >= NNODES) return;
    int p0 = rowptr[n], p1 = rowptr[n + 1];
    float acc = (lane < 11) ? x[n * 11 + lane] : 0.f;
    for (int p = p0; p < p1; p++) {
        int src = eidx[p];
        if (lane < 11) acc += x[src * 11 + lane];
    }
    if (lane < 11) out[n * 11 + lane] = acc;
}

// ================= layer-1 GEMM: [M,11] fp32 @ [11,128] + b -> fp16 + exact stats ======

__global__ __launch_bounds__(256) void gemm11(const float* __restrict__ A,
                                              const float* __restrict__ W,
                                              const float* __restrict__ b,
                                              us_t* __restrict__ C,
                                              float* __restrict__ sums,
                                              float* __restrict__ sumsq) {
    __shared__ float sW[11 * 128];
    __shared__ float sArows[64 * 11];
    int tid = threadIdx.x;
    for (int i = tid; i < 11 * 128; i += 256) sW[i] = W[i];
    int r0 = blockIdx.x * 64;
    for (int i = tid; i < 64 * 11; i += 256) {
        int r = i / 11, c = i - r * 11;
        sArows[i] = (r0 + r < NNODES) ? A[(r0 + r) * 11 + c] : 0.f;
    }
    __syncthreads();
    int col = tid & 127;
    int half = tid >> 7;
    float bias = b[col];
    float cs = 0.f, cq = 0.f;
    for (int rr = half * 32; rr < half * 32 + 32; rr++) {
        int row = r0 + rr;
        if (row < NNODES) {
            float acc = bias;
            #pragma unroll
            for (int k = 0; k < 11; k++) acc += sArows[rr * 11 + k] * sW[k * 128 + col];
            C[(size_t)row * 128 + col] = f2h(acc);
            cs += acc;
            cq += acc * acc;
        }
    }
    __syncthreads();
    sArows[tid] = cs;
    sArows[256 + tid] = cq;
    __syncthreads();
    if (tid < 128) {
        atomicAdd(&sums[tid], sArows[tid] + sArows[tid + 128]);
        atomicAdd(&sumsq[tid], sArows[256 + tid] + sArows[256 + tid + 128]);
    }
}

// ================= MFMA GEMM v8 — m97-style K-loop + LDS-staged C epilogue ==========
// (R14-proven structure; stats now block-combined in LDS -> 256 atomics/block.)
// C[M,N] = A'[M,K_] @ Wt[N,K_]^T + bias, + exact column stats (fp32 acc).
// 128x128 tile, BK=32, 4 waves of 64x64 (4x4 MFMA 16x16x32).
// AMODE 0: A bf16 (async global_load_lds). AMODE 2: A fp16 + BN+relu->bf16.
// OMODE 0: C bf16. OMODE 2: C fp16.  C staged through LDS then us8-coalesced.
// COLS=2: block remap so paired column-blocks share an XCD (A L2 reuse).

template <int K_, int AMODE, int OMODE, int COLS>
__global__ __launch_bounds__(256, 4) void gemm_v8(
    const void* __restrict__ Ap, const us_t* __restrict__ Wt,
    const float* __restrict__ bias,
    const float* __restrict__ sums_in, const float* __restrict__ sumsq_in,
    const float* __restrict__ gma, const float* __restrict__ bet, float invM,
    us_t* __restrict__ Cp, float* __restrict__ sums, float* __restrict__ sumsq,
    int M, int N, int nrows) {
    __shared__ us_t sAB[2 * 128 * 32];            // 16 KB: sA | sB, reused for stats + C
    __shared__ float sST[(AMODE >= 1) ? 2 * K_ : 2];
    us_t* sA = sAB;
    us_t* sB = sAB + 128 * 32;

    int rowblk, colblk;
    if (COLS == 1) {
        rowblk = blockIdx.x;
        colblk = 0;
    } else {
        int g = blockIdx.x;
        rowblk = (g >> 4) * 8 + (g & 7);
        colblk = (g >> 3) & 1;
        if (rowblk >= nrows) return;   // uniform whole-block exit (before barriers)
    }
    const int bm = rowblk * 128;
    const int bn = colblk * 128;

    const int tid = threadIdx.x;
    const int lane = tid & 63;
    const int wave = tid >> 6;
    const int wm = wave >> 1, wn = wave & 1;
    const int lrow = lane & 15, lquad = lane >> 4;

    if (AMODE >= 1) {
        if (tid < K_) {
            float m = sums_in[tid] * invM;
            float va = sumsq_in[tid] * invM - m * m;
            float sc = gma[tid] * rsqrtf(va + BN_EPS);
            sST[tid] = sc;
            sST[K_ + tid] = bet[tid] - m * sc;
        }
        __syncthreads();
    }

    f32x4 acc[4][4] = {};

    // staging chunk ids: this thread handles chunks {tid, tid+256} of 512
    const int r0c = tid >> 2, q0c = tid & 3;            // chunk tid
    const int r1c = (tid + 256) >> 2, q1c = tid & 3;    // chunk tid+256

    #pragma unroll
    for (int kt = 0; kt < K_ / 32; kt++) {
        const int k0 = kt * 32;

        // ---- AMODE>=1: A loads + BN transform in regs (before barrier) ----
        us8 pk[2];
        if (AMODE >= 1) {
            #pragma unroll
            for (int i = 0; i < 2; i++) {
                int row = (i == 0) ? r0c : r1c;
                int kq = (i == 0) ? q0c : q1c;
                int kk = k0 + kq * 8;
                float v[8];
                if (AMODE == 1) {
                    const float* ar = &((const float*)Ap)[(size_t)(bm + row) * K_ + kk];
                    float4 v0 = *(const float4*)ar;
                    float4 v1 = *(const float4*)(ar + 4);
                    v[0] = v0.x; v[1] = v0.y; v[2] = v0.z; v[3] = v0.w;
                    v[4] = v1.x; v[5] = v1.y; v[6] = v1.z; v[7] = v1.w;
                } else {
                    us8 u = *(const us8*)&((const us_t*)Ap)[(size_t)(bm + row) * K_ + kk];
                    #pragma unroll
                    for (int q = 0; q < 8; q++) v[q] = h2f(u[q]);
                }
                float4 s0 = *(const float4*)&sST[kk];
                float4 s1 = *(const float4*)&sST[kk + 4];
                float4 t0 = *(const float4*)&sST[K_ + kk];
                float4 t1 = *(const float4*)&sST[K_ + kk + 4];
                us8 o;
                o[0] = f2b(fmaxf(0.f, v[0] * s0.x + t0.x));
                o[1] = f2b(fmaxf(0.f, v[1] * s0.y + t0.y));
                o[2] = f2b(fmaxf(0.f, v[2] * s0.z + t0.z));
                o[3] = f2b(fmaxf(0.f, v[3] * s0.w + t0.w));
                o[4] = f2b(fmaxf(0.f, v[4] * s1.x + t1.x));
                o[5] = f2b(fmaxf(0.f, v[5] * s1.y + t1.y));
                o[6] = f2b(fmaxf(0.f, v[6] * s1.z + t1.z));
                o[7] = f2b(fmaxf(0.f, v[7] * s1.w + t1.w));
                pk[i] = o;
            }
        }

        __syncthreads();   // all waves done reading LDS tile kt-1

        // ---- stage B via async global->LDS ----
        {
            glds16(&Wt[(size_t)(bn + r0c) * K_ + k0 + q0c * 8], &sB[(wave * 64) * 8]);
            glds16(&Wt[(size_t)(bn + r1c) * K_ + k0 + q1c * 8], &sB[(256 + wave * 64) * 8]);
        }
        // ---- stage A ----
        if (AMODE == 0) {
            const us_t* A = (const us_t*)Ap;
            glds16(&A[(size_t)(bm + r0c) * K_ + k0 + q0c * 8], &sA[(wave * 64) * 8]);
            glds16(&A[(size_t)(bm + r1c) * K_ + k0 + q1c * 8], &sA[(256 + wave * 64) * 8]);
        } else {
            *(us8*)&sA[(size_t)tid * 8] = pk[0];
            *(us8*)&sA[(size_t)(tid + 256) * 8] = pk[1];
        }

        __syncthreads();   // staging complete

        // ---- fragments + MFMA ----
        bf16x8 af[4], bfr[4];
        #pragma unroll
        for (int i = 0; i < 4; i++)
            af[i] = as_bf(*(const us8*)&sA[(wm * 64 + i * 16 + lrow) * 32 + lquad * 8]);
        #pragma unroll
        for (int j = 0; j < 4; j++)
            bfr[j] = as_bf(*(const us8*)&sB[(wn * 64 + j * 16 + lrow) * 32 + lquad * 8]);
        #pragma unroll
        for (int i = 0; i < 4; i++)
            #pragma unroll
            for (int j = 0; j < 4; j++)
                acc[i][j] = __builtin_amdgcn_mfma_f32_16x16x32_bf16(af[i], bfr[j],
                                                                    acc[i][j], 0, 0, 0);
    }

    // ---- stats: per-wave partials -> LDS combine -> 256 atomics/block ----
    __syncthreads();                       // K-loop LDS reads done; reuse sAB
    float* pf = (float*)sAB;               // [0,256): sums partials; [256,512): sumsq
    #pragma unroll
    for (int j = 0; j < 4; j++) {
        int coll = wn * 64 + j * 16 + lrow;
        float bcol = bias[bn + coll];
        float cs = 0.f, cq = 0.f;
        #pragma unroll
        for (int i = 0; i < 4; i++) {
            int rb = bm + wm * 64 + i * 16 + lquad * 4;
            #pragma unroll
            for (int r = 0; r < 4; r++) {
                if (rb + r < M) {
                    float zv = acc[i][j][r] + bcol;
                    cs += zv;
                    cq += zv * zv;
                }
            }
        }
        cs += __shfl_xor(cs, 16); cs += __shfl_xor(cs, 32);
        cq += __shfl_xor(cq, 16); cq += __shfl_xor(cq, 32);
        if (lquad == 0) {
            pf[wm * 128 + coll] = cs;
            pf[256 + wm * 128 + coll] = cq;
        }
    }
    __syncthreads();
    if (tid < 128) {
        atomicAdd(&sums[bn + tid], pf[tid] + pf[128 + tid]);
        atomicAdd(&sumsq[bn + tid], pf[256 + tid] + pf[384 + tid]);
    }

    // ---- C store via LDS staging: 2 passes of 64 rows x 128 cols (16 KB) ----
    #pragma unroll
    for (int p = 0; p < 2; p++) {
        __syncthreads();   // prior pf reads / pass stream-out complete
        if (wm == p) {
            #pragma unroll
            for (int j = 0; j < 4; j++) {
                int coll = wn * 64 + j * 16 + lrow;
                float bcol = bias[bn + coll];
                #pragma unroll
                for (int i = 0; i < 4; i++) {
                    int rl = i * 16 + lquad * 4;
                    #pragma unroll
                    for (int r = 0; r < 4; r++) {
                        float zv = acc[i][j][r] + bcol;
                        sAB[(rl + r) * 128 + coll] = (OMODE == 0) ? f2b(zv) : f2h(zv);
                    }
                }
            }
        }
        __syncthreads();
        #pragma unroll
        for (int k = 0; k < 4; k++) {      // 1024 us8 chunks, 4/thread
            int c = tid + 256 * k;
            int row = c >> 4, cw = c & 15;
            int grow = bm + p * 64 + row;
            if (grow < M)
                *(us8*)&Cp[(size_t)grow * N + bn + cw * 8] =
                    *(const us8*)&sAB[row * 128 + cw * 8];
        }
    }
}

// ================= pool (fp16 z in, BN finalize+apply+relu fused, atomic out) ==========

__global__ void pool_bn_h(const us_t* __restrict__ z, const float* __restrict__ sums,
                          const float* __restrict__ sumsq, const float* __restrict__ gw,
                          const float* __restrict__ bw, float invM,
                          const int* __restrict__ batch, float* __restrict__ hg) {
    int f = threadIdx.x;  // 256
    float m = sums[f] * invM;
    float va = sumsq[f] * invM - m * m;
    float sv = gw[f] * rsqrtf(va + BN_EPS);
    float tv = bw[f] - m * sv;
    int n0 = blockIdx.x * 32;
    int n1 = min(n0 + 32, NNODES);
    float acc = 0.f;
    int gc = batch[n0];
    for (int n = n0; n < n1; n++) {
        int g = batch[n];
        if (g != gc) {
            atomicAdd(&hg[gc * 256 + f], acc);
            acc = 0.f;
            gc = g;
        }
        acc += fmaxf(0.f, h2f(z[(size_t)n * 256 + f]) * sv + tv);
    }
    atomicAdd(&hg[gc * 256 + f], acc);
}

// ================= head GEMM fp32 (M=1000,K=256,N=128) + stats =================

#define GBM 128
#define GBN 128
#define GBK 16
#define LDA 132

__global__ __launch_bounds__(256) void gemm_f32_head(
    const float* __restrict__ A, const float* __restrict__ W, const float* __restrict__ bias,
    float* __restrict__ C, float* __restrict__ sums, float* __restrict__ sumsq,
    int M, int K, int N) {
    __shared__ float smem[2 * GBK * LDA];
    float* As = smem;
    float* Ws = smem + GBK * LDA;

    const int bm = blockIdx.y * GBM;
    const int bn = blockIdx.x * GBN;
    const int tid = threadIdx.x;
    const int tm = tid >> 4;
    const int tn = tid & 15;

    float acc[2][2][4][4] = {};

    for (int k0 = 0; k0 < K; k0 += GBK) {
        #pragma unroll
        for (int i = 0; i < 2; i++) {
            int id = tid + 256 * i;
            int row = id >> 2;
            int kq = id & 3;
            int gr = bm + row;
            int kk = k0 + kq * 4;
            float4 a4 = make_float4(0.f, 0.f, 0.f, 0.f);
            if (gr < M && kk < K) a4 = *(const float4*)&A[(size_t)gr * K + kk];
            As[(kq * 4 + 0) * LDA + row] = a4.x;
            As[(kq * 4 + 1) * LDA + row] = a4.y;
            As[(kq * 4 + 2) * LDA + row] = a4.z;
            As[(kq * 4 + 3) * LDA + row] = a4.w;
        }
        #pragma unroll
        for (int i = 0; i < 2; i++) {
            int id = tid + 256 * i;
            int kl = id >> 5;
            int c = id & 31;
            int kk = k0 + kl;
            float4 w4 = make_float4(0.f, 0.f, 0.f, 0.f);
            if (kk < K && bn + c * 4 < N) w4 = *(const float4*)&W[(size_t)kk * N + bn + c * 4];
            *(float4*)&Ws[kl * LDA + c * 4] = w4;
        }
        __syncthreads();
        #pragma unroll
        for (int k = 0; k < GBK; k++) {
            float4 a0 = *(float4*)&As[k * LDA + tm * 4];
            float4 a1 = *(float4*)&As[k * LDA + 64 + tm * 4];
            float4 w0 = *(float4*)&Ws[k * LDA + tn * 4];
            float4 w1 = *(float4*)&Ws[k * LDA + 64 + tn * 4];
            float ar[2][4] = {{a0.x, a0.y, a0.z, a0.w}, {a1.x, a1.y, a1.z, a1.w}};
            float wr[2][4] = {{w0.x, w0.y, w0.z, w0.w}, {w1.x, w1.y, w1.z, w1.w}};
            #pragma unroll
            for (int ri = 0; ri < 2; ri++)
                #pragma unroll
                for (int ci = 0; ci < 2; ci++)
                    #pragma unroll
                    for (int ii = 0; ii < 4; ii++)
                        #pragma unroll
                        for (int jj = 0; jj < 4; jj++)
                            acc[ri][ci][ii][jj] += ar[ri][ii] * wr[ci][jj];
        }
        __syncthreads();
    }

    float colsum[2][4] = {};
    float colsq[2][4] = {};
    #pragma unroll
    for (int ci = 0; ci < 2; ci++) {
        int colbase = bn + ci * 64 + tn * 4;
        if (colbase >= N) continue;
        float4 b4 = *(const float4*)&bias[colbase];
        float br[4] = {b4.x, b4.y, b4.z, b4.w};
        #pragma unroll
        for (int ri = 0; ri < 2; ri++) {
            #pragma unroll
            for (int ii = 0; ii < 4; ii++) {
                int row = bm + ri * 64 + tm * 4 + ii;
                if (row < M) {
                    float z0 = acc[ri][ci][ii][0] + br[0];
                    float z1 = acc[ri][ci][ii][1] + br[1];
                    float z2 = acc[ri][ci][ii][2] + br[2];
                    float z3 = acc[ri][ci][ii][3] + br[3];
                    *(float4*)&C[(size_t)row * N + colbase] = make_float4(z0, z1, z2, z3);
                    colsum[ci][0] += z0; colsq[ci][0] += z0 * z0;
                    colsum[ci][1] += z1; colsq[ci][1] += z1 * z1;
                    colsum[ci][2] += z2; colsq[ci][2] += z2 * z2;
                    colsum[ci][3] += z3; colsq[ci][3] += z3 * z3;
                }
            }
        }
    }
    __syncthreads();
    float* ps = smem;
    float* pq = smem + 2048;
    #pragma unroll
    for (int ci = 0; ci < 2; ci++)
        #pragma unroll
        for (int jj = 0; jj < 4; jj++) {
            int cl = ci * 64 + tn * 4 + jj;
            ps[tm * 128 + cl] = colsum[ci][jj];
            pq[tm * 128 + cl] = colsq[ci][jj];
        }
    __syncthreads();
    if (tid < 128 && bn + tid < N) {
        float s = 0.f, q = 0.f;
        #pragma unroll
        for (int i = 0; i < 16; i++) {
            s += ps[i * 128 + tid];
            q += pq[i * 128 + tid];
        }
        atomicAdd(&sums[bn + tid], s);
        atomicAdd(&sumsq[bn + tid], q);
    }
}

// ================= final head GEMV (BN finalize+apply+relu fused) =================

__global__ void final_gemv_raw(const float* __restrict__ hg2, const float* __restrict__ sums,
                               const float* __restrict__ sumsq, const float* __restrict__ gw,
                               const float* __restrict__ bw, float invM,
                               const float* __restrict__ fw2, const float* __restrict__ fb2,
                               float* __restrict__ out) {
    int g = blockIdx.x;
    int l = threadIdx.x;  // 64
    float m0 = sums[l] * invM, va0 = sumsq[l] * invM - m0 * m0;
    float s0 = gw[l] * rsqrtf(va0 + BN_EPS), t0 = bw[l] - m0 * s0;
    float m1 = sums[64 + l] * invM, va1 = sumsq[64 + l] * invM - m1 * m1;
    float s1 = gw[64 + l] * rsqrtf(va1 + BN_EPS), t1 = bw[64 + l] - m1 * s1;
    float a0 = fmaxf(0.f, hg2[g * 128 + l] * s0 + t0) * fw2[l];
    float a1 = fmaxf(0.f, hg2[g * 128 + 64 + l] * s1 + t1) * fw2[64 + l];
    float v = a0 + a1;
    #pragma unroll
    for (int o = 32; o > 0; o >>= 1) v += __shfl_down(v, o);
    if (l == 0) out[g] = v + fb2[0];
}

// ================= launch =================

extern "C" void kernel_launch(void* const* d_in, const int* in_sizes, int n_in,
                              void* d_out, int out_size, void* d_ws, size_t ws_size,
                              hipStream_t stream) {
    const float* x = (const float*)d_in[0];
    const int* ei = (const int*)d_in[1];
    const int* batch = (const int*)d_in[2];
    const int* esrc = ei;
    const int* edst = ei + NEDGES;

    const float* l1w = (const float*)d_in[3],  *l1b = (const float*)d_in[4],
               * l1g = (const float*)d_in[5],  *l1be = (const float*)d_in[6];
    const float* l2w = (const float*)d_in[7],  *l2b = (const float*)d_in[8],
               * l2g = (const float*)d_in[9],  *l2be = (const float*)d_in[10];
    const float* l3w = (const float*)d_in[11], *l3b = (const float*)d_in[12],
               * l3g = (const float*)d_in[13], *l3be = (const float*)d_in[14];
    const float* l4w = (const float*)d_in[15], *l4b = (const float*)d_in[16],
               * l4g = (const float*)d_in[17], *l4be = (const float*)d_in[18];
    const float* l5w = (const float*)d_in[19], *l5b = (const float*)d_in[20],
               * l5g = (const float*)d_in[21], *l5be = (const float*)d_in[22];
    const float* l6w = (const float*)d_in[23], *l6b = (const float*)d_in[24],
               * l6g = (const float*)d_in[25], *l6be = (const float*)d_in[26];
    const float* fw1 = (const float*)d_in[27], *fb1 = (const float*)d_in[28],
               * fg  = (const float*)d_in[29], *fbe = (const float*)d_in[30];
    const float* fw2 = (const float*)d_in[31], *fb2 = (const float*)d_in[32];

    // ---- workspace carve ----
    // F0h: fp16 z1/z3/z5 [MPAD,256]
    // U region [MPAD,512] us: Ba (bf16 agg) | Bz (bf16 z2/z4, then fp16 z6)
    us_t* F0h = (us_t*)d_ws;                          // [MPAD,256] fp16
    us_t* Ba = F0h + (size_t)MPAD * 256;              // [MPAD,256] bf16 (agg)
    us_t* Bz = Ba + (size_t)MPAD * 256;               // [MPAD,256] bf16 z2/z4 -> fp16 z6
    us_t* wt2 = Bz + (size_t)MPAD * 256;              // [128][128]
    us_t* wt3 = wt2 + 128 * 128;                      // [256][128]
    us_t* wt4 = wt3 + 256 * 128;                      // [256][256]
    us_t* wt5 = wt4 + 256 * 256;
    us_t* wt6 = wt5 + 256 * 256;
    float* agg11 = (float*)(wt6 + 256 * 256);         // [50000][11]
    float* hg = agg11 + (size_t)NNODES * 11;          // [1000][256]
    float* hg2 = hg + NGRAPHS * 256;                  // [1000][128]
    float* stats = hg2 + NGRAPHS * 128;               // 7 x 512 (sums|sumsq)
    int* deg = (int*)(stats + 7 * 512);               // [50001]
    int* rowptr = deg + (NNODES + 1);
    int* cursor = rowptr + (NNODES + 1);
    int* chunkTot = cursor + (NNODES + 1);            // [64]
    int* tmpscan = chunkTot + 64;
    int* eidx = tmpscan + (NNODES + 1);               // [800000]

    // zero hg + hg2 + stats + deg (contiguous)
    {
        int zn = NGRAPHS * 256 + NGRAPHS * 128 + 7 * 512 + (NNODES + 1);
        zero_f32<<<(zn + 255) / 256, 256, 0, stream>>>(hg, zn);
    }

    // CSR
    csr_hist<<<(NEDGES + 255) / 256, 256, 0, stream>>>(edst, deg, NEDGES);
    int nchunks = (NNODES + 1023) / 1024;   // 49
    csr_scan1<<<nchunks, 1024, 0, stream>>>(deg, tmpscan, chunkTot, NNODES);
    csr_scan3<<<(NNODES + 255) / 256, 256, 0, stream>>>(deg, tmpscan, chunkTot, rowptr,
                                                        cursor, NNODES, nchunks);
    csr_fill<<<(NEDGES + 255) / 256, 256, 0, stream>>>(esrc, edst, cursor, eidx, NEDGES);

    // weight converts
    wt_convert_all<<<(245760 + 255) / 256, 256, 0, stream>>>(l2w, l3w, l4w, l5w, l6w,
                                                             wt2, wt3, wt4, wt5, wt6);

    auto st = [&](int i) { return stats + i * 512; };
    const float invN = 1.0f / (float)NNODES;
    const float invG = 1.0f / (float)NGRAPHS;
    const int NRB = MPAD / 128;              // 391
    const int NSWZ = ((NRB + 7) / 8) * 16;   // 784 swizzled blocks for COLS=2

    // ---- conv1: agg(x) -> z1=F0h fp16 [M,128] -> [BN0 fused] l2 -> z2=Bz bf16 ----
    gin_gather11<<<(NNODES + 15) / 16, 256, 0, stream>>>(x, rowptr, eidx, agg11);
    gemm11<<<(NNODES + 63) / 64, 256, 0, stream>>>(agg11, l1w, l1b, F0h, st(0), st(0) + 256);
    gemm_v8<128, 2, 0, 1><<<NRB, 256, 0, stream>>>(
        F0h, wt2, l2b, st(0), st(0) + 256, l1g, l1be, invN,
        Bz, st(1), st(1) + 256, NNODES, 128, NRB);

    // ---- conv2: gather(BN1) z2 -> agg2=Ba bf16 [M,128] -> l3 -> z3=F0h fp16 [M,256]
    //            -> [BN2 fused] l4 -> z4=Bz bf16 [M,256] ----
    gin_gather_bn128<<<(NNODES + 15) / 16, 256, 0, stream>>>(
        Bz, st(1), st(1) + 256, l2g, l2be, invN, rowptr, eidx, Ba);
    gemm_v8<128, 0, 2, 2><<<NSWZ, 256, 0, stream>>>(
        Ba, wt3, l3b, nullptr, nullptr, nullptr, nullptr, 0.f,
        F0h, st(2), st(2) + 256, NNODES, 256, NRB);
    gemm_v8<256, 2, 0, 2><<<NSWZ, 256, 0, stream>>>(
        F0h, wt4, l4b, st(2), st(2) + 256, l3g, l3be, invN,
        Bz, st(3), st(3) + 256, NNODES, 256, NRB);

    // ---- conv3: gather(BN3) z4 -> agg3=Ba bf16 [M,256] -> l5 -> z5=F0h fp16
    //            -> [BN4 fused] l6 -> z6=Bz fp16 (z4 dead) ----
    gin_gather_bn256<<<(NNODES + 7) / 8, 256, 0, stream>>>(
        Bz, st(3), st(3) + 256, l4g, l4be, invN, rowptr, eidx, Ba);
    gemm_v8<256, 0, 2, 2><<<NSWZ, 256, 0, stream>>>(
        Ba, wt5, l5b, nullptr, nullptr, nullptr, nullptr, 0.f,
        F0h, st(4), st(4) + 256, NNODES, 256, NRB);
    gemm_v8<256, 2, 2, 2><<<NSWZ, 256, 0, stream>>>(
        F0h, wt6, l6b, st(4), st(4) + 256, l5g, l5be, invN,
        Bz, st(5), st(5) + 256, NNODES, 256, NRB);

    // ---- pool (BN5 fused, fp16 z6) + head ----
    pool_bn_h<<<(NNODES + 31) / 32, 256, 0, stream>>>(
        Bz, st(5), st(5) + 256, l6g, l6be, invN, batch, hg);
    gemm_f32_head<<<dim3(1, 8), 256, 0, stream>>>(hg, fw1, fb1, hg2, st(6), st(6) + 256,
                                                  NGRAPHS, 256, 128);
    final_gemv_raw<<<NGRAPHS, 64, 0, stream>>>(hg2, st(6), st(6) + 256, fg, fbe, invG,
                                               fw2, fb2, (float*)d_out);
}